// Round 6
// baseline (794.347 us; speedup 1.0000x reference)
//
#include <hip/hip_runtime.h>
#include <hip/hip_cooperative_groups.h>
#include <hip/hip_fp16.h>
#include <math.h>

namespace cg = cooperative_groups;

#define N_NODES    1000000
#define N_EDGES    16000000
#define NUM_GRAPHS 64
#define LATENT     128
#define MAX_BLOCKS 2048

// ws layout (bytes):
//   [0, 32K)        edge partials: double2[MAX_BLOCKS] (S1,S2)
//   [32K, 48K)      recon partials: double[MAX_BLOCKS]
//   [49152, +8)     kl partial: double[1]
//   [49216, +1.5M)  graph partials: float[MAX_BLOCKS][192] (x64,y64,cnt64)
//   [2M, 2M+4M)     packed half2 pred table
#define EDGE_PART_OFF  0
#define RECON_PART_OFF 32768
#define KL_PART_OFF    49152
#define GSUM_PART_OFF  49216
#define PACKED_OFF     2097152
#define WS_NEEDED      (PACKED_OFF + 4ull * N_NODES)

typedef int vint4 __attribute__((ext_vector_type(4)));

// ---------------- fused cooperative kernel ----------------
// Phase 1: node stream (recon, per-graph sums, pack half2 table, KL on block 0)
// grid.sync()
// Phase 2: edge gathers from packed table -> per-block partials
// grid.sync()
// Phase 3: block 0 reduces all partials and writes the scalar loss.
__global__ __launch_bounds__(256, 8)
void fused_all(const float2* __restrict__ pred,
               const float2* __restrict__ targ,
               const int*    __restrict__ batch,
               const float*  __restrict__ mu,
               const float*  __restrict__ logvar,
               const int*    __restrict__ ei,
               const int*    __restrict__ epoch_p,
               float*        __restrict__ out,
               double* __restrict__ edge_part,
               double* __restrict__ recon_part,
               double* __restrict__ kl_part,
               float*  __restrict__ gsum_part,
               unsigned* __restrict__ packed) {
    __shared__ float sgx[NUM_GRAPHS];
    __shared__ float sgy[NUM_GRAPHS];
    __shared__ int   scnt[NUM_GRAPHS];
    __shared__ double smem[8];
    __shared__ double sx_s[256], sy_s[256], sc_s[256];

    const int lane = threadIdx.x & 63;
    const int wid  = threadIdx.x >> 6;

    // ---------- Phase 1: nodes + KL ----------
    for (int g = threadIdx.x; g < NUM_GRAPHS; g += blockDim.x) {
        sgx[g] = 0.f; sgy[g] = 0.f; scnt[g] = 0;
    }
    __syncthreads();

    float recon = 0.f;
    const int idx = blockIdx.x * blockDim.x + threadIdx.x;
    const int stride = gridDim.x * blockDim.x;
    for (int n = idx; n < N_NODES; n += stride) {
        float2 p = pred[n];
        float2 t = targ[n];
        float dx = p.x - t.x, dy = p.y - t.y;
        recon += dx * dx + dy * dy;

        __half2 h = __floats2half2_rn(p.x, p.y);
        packed[n] = *reinterpret_cast<unsigned*>(&h);

        int b = batch[n];
        // batch is sorted: waves are almost always graph-uniform.
        unsigned long long act = __ballot(1);
        int b0 = __shfl(b, 0);
        bool fast = (act == ~0ull) && (__ballot(b == b0) == act);
        if (fast) {
            float sx = p.x, sy = p.y;
            #pragma unroll
            for (int off = 32; off > 0; off >>= 1) {
                sx += __shfl_xor(sx, off);
                sy += __shfl_xor(sy, off);
            }
            if (lane == 0) {
                atomicAdd(&sgx[b0], sx);
                atomicAdd(&sgy[b0], sy);
                atomicAdd(&scnt[b0], 64);
            }
        } else {
            atomicAdd(&sgx[b], p.x);
            atomicAdd(&sgy[b], p.y);
            atomicAdd(&scnt[b], 1);
        }
    }

    // recon -> private slot
    double r = (double)recon;
    #pragma unroll
    for (int off = 32; off > 0; off >>= 1) r += __shfl_down(r, off);
    if (lane == 0) smem[wid] = r;
    __syncthreads();
    if (threadIdx.x == 0)
        recon_part[blockIdx.x] = smem[0] + smem[1] + smem[2] + smem[3];

    // graph partials -> private slot
    {
        float* slot = gsum_part + (size_t)blockIdx.x * 192;
        for (int g = threadIdx.x; g < NUM_GRAPHS; g += blockDim.x) {
            slot[g]       = sgx[g];
            slot[64 + g]  = sgy[g];
            slot[128 + g] = (float)scnt[g];
        }
    }

    // KL on block 0
    if (blockIdx.x == 0) {
        double s = 0.0;
        for (int t = threadIdx.x; t < NUM_GRAPHS * LATENT; t += blockDim.x) {
            float m = mu[t], lv = logvar[t];
            s += (double)(1.0f + lv - m * m - expf(lv));
        }
        #pragma unroll
        for (int off = 32; off > 0; off >>= 1) s += __shfl_down(s, off);
        __syncthreads();
        if (lane == 0) smem[wid] = s;
        __syncthreads();
        if (threadIdx.x == 0)
            kl_part[0] = smem[0] + smem[1] + smem[2] + smem[3];
    }

    cg::this_grid().sync();

    // ---------- Phase 2: edges ----------
    {
        float s1 = 0.f, s2 = 0.f;
        const int ngroups = N_EDGES / 4;
        const vint4* eia = (const vint4*)ei;
        const vint4* eib = (const vint4*)(ei + N_EDGES);

        int g = idx;
        if (g < ngroups) {
            vint4 a = __builtin_nontemporal_load(eia + g);
            vint4 b = __builtin_nontemporal_load(eib + g);
            while (true) {
                unsigned pa0 = packed[a.x], pb0 = packed[b.x];
                unsigned pa1 = packed[a.y], pb1 = packed[b.y];
                unsigned pa2 = packed[a.z], pb2 = packed[b.z];
                unsigned pa3 = packed[a.w], pb3 = packed[b.w];

                const int gn = g + stride;
                const bool more = gn < ngroups;
                vint4 an = {0, 0, 0, 0}, bn = {0, 0, 0, 0};
                if (more) {
                    an = __builtin_nontemporal_load(eia + gn);
                    bn = __builtin_nontemporal_load(eib + gn);
                }

                {
                    __half2 ha = *reinterpret_cast<__half2*>(&pa0);
                    __half2 hb = *reinterpret_cast<__half2*>(&pb0);
                    float2 fa = __half22float2(ha);
                    float2 fb = __half22float2(hb);
                    float dx = fa.x - fb.x, dy = fa.y - fb.y;
                    float l2 = dx * dx + dy * dy;
                    s2 += l2; s1 += sqrtf(l2);
                }
                {
                    __half2 ha = *reinterpret_cast<__half2*>(&pa1);
                    __half2 hb = *reinterpret_cast<__half2*>(&pb1);
                    float2 fa = __half22float2(ha);
                    float2 fb = __half22float2(hb);
                    float dx = fa.x - fb.x, dy = fa.y - fb.y;
                    float l2 = dx * dx + dy * dy;
                    s2 += l2; s1 += sqrtf(l2);
                }
                {
                    __half2 ha = *reinterpret_cast<__half2*>(&pa2);
                    __half2 hb = *reinterpret_cast<__half2*>(&pb2);
                    float2 fa = __half22float2(ha);
                    float2 fb = __half22float2(hb);
                    float dx = fa.x - fb.x, dy = fa.y - fb.y;
                    float l2 = dx * dx + dy * dy;
                    s2 += l2; s1 += sqrtf(l2);
                }
                {
                    __half2 ha = *reinterpret_cast<__half2*>(&pa3);
                    __half2 hb = *reinterpret_cast<__half2*>(&pb3);
                    float2 fa = __half22float2(ha);
                    float2 fb = __half22float2(hb);
                    float dx = fa.x - fb.x, dy = fa.y - fb.y;
                    float l2 = dx * dx + dy * dy;
                    s2 += l2; s1 += sqrtf(l2);
                }

                if (!more) break;
                g = gn; a = an; b = bn;
            }
        }

        double r1 = (double)s1, r2 = (double)s2;
        #pragma unroll
        for (int off = 32; off > 0; off >>= 1) {
            r1 += __shfl_down(r1, off);
            r2 += __shfl_down(r2, off);
        }
        __syncthreads();  // smem reuse
        if (lane == 0) { smem[wid] = r1; smem[4 + wid] = r2; }
        __syncthreads();
        if (threadIdx.x == 0) {
            edge_part[2 * blockIdx.x]     = smem[0] + smem[1] + smem[2] + smem[3];
            edge_part[2 * blockIdx.x + 1] = smem[4] + smem[5] + smem[6] + smem[7];
        }
    }

    cg::this_grid().sync();

    // ---------- Phase 3: finalize on block 0 ----------
    if (blockIdx.x == 0) {
        const int t = threadIdx.x;
        const int NB = gridDim.x;

        double reconv = 0.0;
        for (int b = t; b < NB; b += 256) reconv += recon_part[b];
        double s1 = 0.0, s2 = 0.0;
        for (int b = t; b < NB; b += 256) {
            s1 += edge_part[2 * b];
            s2 += edge_part[2 * b + 1];
        }

        {
            const int g = t & 63, q = t >> 6;
            double gx = 0.0, gy = 0.0, gc = 0.0;
            for (int b = q; b < NB; b += 4) {
                const float* slot = gsum_part + (size_t)b * 192;
                gx += slot[g]; gy += slot[64 + g]; gc += slot[128 + g];
            }
            sx_s[t] = gx; sy_s[t] = gy; sc_s[t] = gc;
        }
        __syncthreads();

        double drift = 0.0;
        if (t < 64) {
            double X = sx_s[t] + sx_s[t + 64] + sx_s[t + 128] + sx_s[t + 192];
            double Y = sy_s[t] + sy_s[t + 64] + sy_s[t + 128] + sy_s[t + 192];
            double C = sc_s[t] + sc_s[t + 64] + sc_s[t + 128] + sc_s[t + 192];
            double mx = X / C, my = Y / C;
            drift = mx * mx + my * my;
        }
        #pragma unroll
        for (int off = 32; off > 0; off >>= 1) drift += __shfl_down(drift, off);

        // three block reductions via smem
        #pragma unroll
        for (int off = 32; off > 0; off >>= 1) reconv += __shfl_down(reconv, off);
        __syncthreads();
        if (lane == 0) smem[wid] = reconv;
        __syncthreads();
        reconv = smem[0] + smem[1] + smem[2] + smem[3];

        #pragma unroll
        for (int off = 32; off > 0; off >>= 1) s1 += __shfl_down(s1, off);
        __syncthreads();
        if (lane == 0) smem[wid] = s1;
        __syncthreads();
        s1 = smem[0] + smem[1] + smem[2] + smem[3];

        #pragma unroll
        for (int off = 32; off > 0; off >>= 1) s2 += __shfl_down(s2, off);
        __syncthreads();
        if (lane == 0) smem[wid] = s2;
        __syncthreads();
        s2 = smem[0] + smem[1] + smem[2] + smem[3];

        if (t == 0) {
            double recon = reconv / (2.0 * (double)N_NODES);
            double lap   = s2 / (double)N_EDGES;
            double arap  = (s2 - s1 * s1 / (double)N_EDGES) / ((double)N_EDGES - 1.0);
            double drft  = drift / (double)NUM_GRAPHS;
            double kl    = -0.5 * kl_part[0] / (double)NUM_GRAPHS;
            int epoch = *epoch_p;
            double beta = (epoch < 10) ? ((double)epoch / 10.0) : 1.0;
            out[0] = (float)(recon + 0.1 * lap + 0.01 * drft + 0.1 * arap + beta * kl);
        }
    }
}

// ---------------- fallback path (ws too small): R5's 3-kernel f32 version ----
__global__ void node_kl_pass_fb(const float2* __restrict__ pred,
                                const float2* __restrict__ targ,
                                const int*    __restrict__ batch,
                                const float*  __restrict__ mu,
                                const float*  __restrict__ logvar,
                                double* __restrict__ recon_part,
                                double* __restrict__ kl_part,
                                float*  __restrict__ gsum_part) {
    __shared__ float sgx[NUM_GRAPHS];
    __shared__ float sgy[NUM_GRAPHS];
    __shared__ int   scnt[NUM_GRAPHS];
    __shared__ double smem[8];

    for (int g = threadIdx.x; g < NUM_GRAPHS; g += blockDim.x) {
        sgx[g] = 0.f; sgy[g] = 0.f; scnt[g] = 0;
    }
    __syncthreads();

    float recon = 0.f;
    const int idx = blockIdx.x * blockDim.x + threadIdx.x;
    const int stride = gridDim.x * blockDim.x;
    for (int n = idx; n < N_NODES; n += stride) {
        float2 p = pred[n];
        float2 t = targ[n];
        float dx = p.x - t.x, dy = p.y - t.y;
        recon += dx * dx + dy * dy;
        int b = batch[n];
        atomicAdd(&sgx[b], p.x);
        atomicAdd(&sgy[b], p.y);
        atomicAdd(&scnt[b], 1);
    }

    double r = (double)recon;
    #pragma unroll
    for (int off = 32; off > 0; off >>= 1) r += __shfl_down(r, off);
    const int lane = threadIdx.x & 63;
    const int wid  = threadIdx.x >> 6;
    if (lane == 0) smem[wid] = r;
    __syncthreads();
    if (threadIdx.x == 0)
        recon_part[blockIdx.x] = smem[0] + smem[1] + smem[2] + smem[3];

    float* slot = gsum_part + (size_t)blockIdx.x * 192;
    for (int g = threadIdx.x; g < NUM_GRAPHS; g += blockDim.x) {
        slot[g]       = sgx[g];
        slot[64 + g]  = sgy[g];
        slot[128 + g] = (float)scnt[g];
    }

    if (blockIdx.x == 0) {
        double s = 0.0;
        for (int t = threadIdx.x; t < NUM_GRAPHS * LATENT; t += blockDim.x) {
            float m = mu[t], lv = logvar[t];
            s += (double)(1.0f + lv - m * m - expf(lv));
        }
        #pragma unroll
        for (int off = 32; off > 0; off >>= 1) s += __shfl_down(s, off);
        __syncthreads();
        if (lane == 0) smem[wid] = s;
        __syncthreads();
        if (threadIdx.x == 0)
            kl_part[0] = smem[0] + smem[1] + smem[2] + smem[3];
    }
}

__global__ void edge_pass_f32_fb(const float2* __restrict__ pred,
                                 const int* __restrict__ ei,
                                 double* __restrict__ edge_part) {
    __shared__ double smem1[8];
    __shared__ double smem2[8];
    float s1 = 0.f, s2 = 0.f;
    const int idx = blockIdx.x * blockDim.x + threadIdx.x;
    const int stride = gridDim.x * blockDim.x;
    for (int e = idx; e < N_EDGES; e += stride) {
        int i = ei[e];
        int j = ei[N_EDGES + e];
        float2 pi = pred[i];
        float2 pj = pred[j];
        float dx = pi.x - pj.x, dy = pi.y - pj.y;
        float l2 = dx * dx + dy * dy;
        s2 += l2;
        s1 += sqrtf(l2);
    }
    double r1 = (double)s1, r2 = (double)s2;
    #pragma unroll
    for (int off = 32; off > 0; off >>= 1) {
        r1 += __shfl_down(r1, off);
        r2 += __shfl_down(r2, off);
    }
    const int lane = threadIdx.x & 63;
    const int wid  = threadIdx.x >> 6;
    if (lane == 0) { smem1[wid] = r1; smem2[wid] = r2; }
    __syncthreads();
    if (threadIdx.x == 0) {
        edge_part[2 * blockIdx.x]     = smem1[0] + smem1[1] + smem1[2] + smem1[3];
        edge_part[2 * blockIdx.x + 1] = smem2[0] + smem2[1] + smem2[2] + smem2[3];
    }
}

__global__ void finalize_fb(const double* __restrict__ edge_part, int n_edge_blocks,
                            const double* __restrict__ recon_part, int n_node_blocks,
                            const double* __restrict__ kl_part,
                            const float*  __restrict__ gsum_part,
                            const int*    __restrict__ epoch_p,
                            float* __restrict__ out) {
    __shared__ double sx_s[256], sy_s[256], sc_s[256];
    __shared__ double sm[8];
    const int t = threadIdx.x;
    const int lane = t & 63, wid = t >> 6;

    double reconv = 0.0;
    for (int b = t; b < n_node_blocks; b += 256) reconv += recon_part[b];
    double s1 = 0.0, s2 = 0.0;
    for (int b = t; b < n_edge_blocks; b += 256) {
        s1 += edge_part[2 * b];
        s2 += edge_part[2 * b + 1];
    }
    {
        const int g = t & 63, q = t >> 6;
        double gx = 0.0, gy = 0.0, gc = 0.0;
        for (int b = q; b < n_node_blocks; b += 4) {
            const float* slot = gsum_part + (size_t)b * 192;
            gx += slot[g]; gy += slot[64 + g]; gc += slot[128 + g];
        }
        sx_s[t] = gx; sy_s[t] = gy; sc_s[t] = gc;
    }
    __syncthreads();

    double drift = 0.0;
    if (t < 64) {
        double X = sx_s[t] + sx_s[t + 64] + sx_s[t + 128] + sx_s[t + 192];
        double Y = sy_s[t] + sy_s[t + 64] + sy_s[t + 128] + sy_s[t + 192];
        double C = sc_s[t] + sc_s[t + 64] + sc_s[t + 128] + sc_s[t + 192];
        double mx = X / C, my = Y / C;
        drift = mx * mx + my * my;
    }
    #pragma unroll
    for (int off = 32; off > 0; off >>= 1) drift += __shfl_down(drift, off);

    #pragma unroll
    for (int off = 32; off > 0; off >>= 1) reconv += __shfl_down(reconv, off);
    __syncthreads(); if (lane == 0) sm[wid] = reconv; __syncthreads();
    reconv = sm[0] + sm[1] + sm[2] + sm[3];
    #pragma unroll
    for (int off = 32; off > 0; off >>= 1) s1 += __shfl_down(s1, off);
    __syncthreads(); if (lane == 0) sm[wid] = s1; __syncthreads();
    s1 = sm[0] + sm[1] + sm[2] + sm[3];
    #pragma unroll
    for (int off = 32; off > 0; off >>= 1) s2 += __shfl_down(s2, off);
    __syncthreads(); if (lane == 0) sm[wid] = s2; __syncthreads();
    s2 = sm[0] + sm[1] + sm[2] + sm[3];

    if (t == 0) {
        double recon = reconv / (2.0 * (double)N_NODES);
        double lap   = s2 / (double)N_EDGES;
        double arap  = (s2 - s1 * s1 / (double)N_EDGES) / ((double)N_EDGES - 1.0);
        double drft  = drift / (double)NUM_GRAPHS;
        double kl    = -0.5 * kl_part[0] / (double)NUM_GRAPHS;
        int epoch = *epoch_p;
        double beta = (epoch < 10) ? ((double)epoch / 10.0) : 1.0;
        out[0] = (float)(recon + 0.1 * lap + 0.01 * drft + 0.1 * arap + beta * kl);
    }
}

extern "C" void kernel_launch(void* const* d_in, const int* in_sizes, int n_in,
                              void* d_out, int out_size, void* d_ws, size_t ws_size,
                              hipStream_t stream) {
    const float2* pred   = (const float2*)d_in[0];
    const float2* targ   = (const float2*)d_in[1];
    const int*    ei     = (const int*)d_in[2];
    const int*    batch  = (const int*)d_in[3];
    const float*  mu     = (const float*)d_in[4];
    const float*  logvar = (const float*)d_in[5];
    const int*    epoch  = (const int*)d_in[6];
    float* out = (float*)d_out;

    char* ws = (char*)d_ws;
    double* edge_part  = (double*)(ws + EDGE_PART_OFF);
    double* recon_part = (double*)(ws + RECON_PART_OFF);
    double* kl_part    = (double*)(ws + KL_PART_OFF);
    float*  gsum_part  = (float*)(ws + GSUM_PART_OFF);
    unsigned* packed   = (unsigned*)(ws + PACKED_OFF);

    if (ws_size >= WS_NEEDED) {
        int maxb = 0;
        if (hipOccupancyMaxActiveBlocksPerMultiprocessor(
                &maxb, reinterpret_cast<const void*>(&fused_all), 256, 0) != hipSuccess ||
            maxb <= 0)
            maxb = 4;  // conservative
        int grid = maxb * 256;          // 256 CUs
        if (grid > MAX_BLOCKS) grid = MAX_BLOCKS;

        void* args[] = {(void*)&pred, (void*)&targ, (void*)&batch, (void*)&mu,
                        (void*)&logvar, (void*)&ei, (void*)&epoch, (void*)&out,
                        (void*)&edge_part, (void*)&recon_part, (void*)&kl_part,
                        (void*)&gsum_part, (void*)&packed};
        hipLaunchCooperativeKernel(reinterpret_cast<const void*>(&fused_all),
                                   dim3(grid), dim3(256), args, 0, stream);
    } else {
        node_kl_pass_fb<<<512, 256, 0, stream>>>(pred, targ, batch, mu, logvar,
                                                 recon_part, kl_part, gsum_part);
        edge_pass_f32_fb<<<MAX_BLOCKS, 256, 0, stream>>>(pred, ei, edge_part);
        finalize_fb<<<1, 256, 0, stream>>>(edge_part, MAX_BLOCKS, recon_part, 512,
                                           kl_part, gsum_part, epoch, out);
    }
}

// Round 7
// 382.777 us; speedup vs baseline: 2.0752x; 2.0752x over previous
//
#include <hip/hip_runtime.h>
#include <hip/hip_fp16.h>
#include <math.h>

#define N_NODES    1000000
#define N_EDGES    16000000
#define NUM_GRAPHS 64
#define LATENT     128

#define NODE_BLOCKS 512
#define EDGE_BLOCKS 2048

// ws layout (bytes):
//   [0, 32K)            edge partials: double2[EDGE_BLOCKS] (S1, S2)
//   [32K, 36K)          recon partials: double[NODE_BLOCKS]
//   [36864, +8)         kl partial: double[1]
//   [36872, +384K)      graph partials: float[NODE_BLOCKS][192] (x64,y64,cnt64)
//   [448K, 448K+4M)     packed half2 pred table
#define EDGE_PART_OFF  0
#define RECON_PART_OFF 32768
#define KL_PART_OFF    36864
#define GSUM_PART_OFF  36872
#define PACKED_OFF     458752
#define WS_NEEDED      (PACKED_OFF + 4ull * N_NODES)

typedef int vint4 __attribute__((ext_vector_type(4)));

// ---------------------------------------------------------------- node + KL
__global__ void node_kl_pass(const float4* __restrict__ pred4,
                             const float4* __restrict__ targ4,
                             const int2*   __restrict__ batch2,
                             const float*  __restrict__ mu,
                             const float*  __restrict__ logvar,
                             double* __restrict__ recon_part,   // [NODE_BLOCKS]
                             double* __restrict__ kl_part,      // [1]
                             float*  __restrict__ gsum_part,    // [NODE_BLOCKS][192]
                             uint2*  __restrict__ packed2) {    // may be null
    __shared__ float sgx[NUM_GRAPHS];
    __shared__ float sgy[NUM_GRAPHS];
    __shared__ int   scnt[NUM_GRAPHS];
    __shared__ double smem[8];

    for (int g = threadIdx.x; g < NUM_GRAPHS; g += blockDim.x) {
        sgx[g] = 0.f; sgy[g] = 0.f; scnt[g] = 0;
    }
    __syncthreads();

    const int lane = threadIdx.x & 63;
    const int wid  = threadIdx.x >> 6;

    float recon = 0.f;
    const int idx = blockIdx.x * blockDim.x + threadIdx.x;
    const int stride = gridDim.x * blockDim.x;
    const int npairs = N_NODES / 2;
    for (int n = idx; n < npairs; n += stride) {
        float4 p = pred4[n];
        float4 t = targ4[n];
        float dx0 = p.x - t.x, dy0 = p.y - t.y;
        float dx1 = p.z - t.z, dy1 = p.w - t.w;
        recon += dx0 * dx0 + dy0 * dy0 + dx1 * dx1 + dy1 * dy1;

        if (packed2) {
            __half2 h0 = __floats2half2_rn(p.x, p.y);
            __half2 h1 = __floats2half2_rn(p.z, p.w);
            uint2 u;
            u.x = *reinterpret_cast<unsigned*>(&h0);
            u.y = *reinterpret_cast<unsigned*>(&h1);
            packed2[n] = u;
        }

        int2 bb = batch2[n];
        // batch is sorted: waves are almost always graph-uniform.
        unsigned long long act = __ballot(1);
        int b0 = __shfl(bb.x, 0);
        bool fast = (act == ~0ull) &&
                    (__ballot((bb.x == bb.y) && (bb.x == b0)) == act);
        if (fast) {
            float sx = p.x + p.z, sy = p.y + p.w;
            #pragma unroll
            for (int off = 32; off > 0; off >>= 1) {
                sx += __shfl_xor(sx, off);
                sy += __shfl_xor(sy, off);
            }
            if (lane == 0) {
                atomicAdd(&sgx[b0], sx);
                atomicAdd(&sgy[b0], sy);
                atomicAdd(&scnt[b0], 128);
            }
        } else {
            atomicAdd(&sgx[bb.x], p.x);
            atomicAdd(&sgy[bb.x], p.y);
            atomicAdd(&scnt[bb.x], 1);
            atomicAdd(&sgx[bb.y], p.z);
            atomicAdd(&sgy[bb.y], p.w);
            atomicAdd(&scnt[bb.y], 1);
        }
    }

    // recon -> private slot (no global atomics)
    double r = (double)recon;
    #pragma unroll
    for (int off = 32; off > 0; off >>= 1) r += __shfl_down(r, off);
    if (lane == 0) smem[wid] = r;
    __syncthreads();
    if (threadIdx.x == 0)
        recon_part[blockIdx.x] = smem[0] + smem[1] + smem[2] + smem[3];

    // graph partials -> private 192-float slot
    {
        float* slot = gsum_part + (size_t)blockIdx.x * 192;
        for (int g = threadIdx.x; g < NUM_GRAPHS; g += blockDim.x) {
            slot[g]       = sgx[g];
            slot[64 + g]  = sgy[g];
            slot[128 + g] = (float)scnt[g];
        }
    }

    // KL tail: block 0 only (8192 elements)
    if (blockIdx.x == 0) {
        double s = 0.0;
        for (int t = threadIdx.x; t < NUM_GRAPHS * LATENT; t += blockDim.x) {
            float m = mu[t], lv = logvar[t];
            s += (double)(1.0f + lv - m * m - expf(lv));
        }
        #pragma unroll
        for (int off = 32; off > 0; off >>= 1) s += __shfl_down(s, off);
        __syncthreads();
        if (lane == 0) smem[wid] = s;
        __syncthreads();
        if (threadIdx.x == 0)
            kl_part[0] = smem[0] + smem[1] + smem[2] + smem[3];
    }
}

// ---------------------------------------------------------------- edge pass
__device__ __forceinline__ void edge_flush(float s1, float s2,
                                           double* __restrict__ edge_part,
                                           double* smem1, double* smem2) {
    double r1 = (double)s1, r2 = (double)s2;
    #pragma unroll
    for (int off = 32; off > 0; off >>= 1) {
        r1 += __shfl_down(r1, off);
        r2 += __shfl_down(r2, off);
    }
    const int lane = threadIdx.x & 63;
    const int wid  = threadIdx.x >> 6;
    if (lane == 0) { smem1[wid] = r1; smem2[wid] = r2; }
    __syncthreads();
    if (threadIdx.x == 0) {
        edge_part[2 * blockIdx.x]     = smem1[0] + smem1[1] + smem1[2] + smem1[3];
        edge_part[2 * blockIdx.x + 1] = smem2[0] + smem2[1] + smem2[2] + smem2[3];
    }
}

#define EDGE_ACC(ua, ub) do {                                  \
    __half2 ha = *reinterpret_cast<__half2*>(&(ua));           \
    __half2 hb = *reinterpret_cast<__half2*>(&(ub));           \
    float2 fa = __half22float2(ha);                            \
    float2 fb = __half22float2(hb);                            \
    float dx = fa.x - fb.x, dy = fa.y - fb.y;                  \
    float l2 = dx * dx + dy * dy;                              \
    s2 += l2; s1 += sqrtf(l2);                                 \
} while (0)

// 8 edges (16 random gathers) in flight per thread + prefetched index
// vectors: the gather consume waits at vmcnt(4) while next indices stream.
__global__ void edge_pass_packed(const unsigned* __restrict__ packed,
                                 const int* __restrict__ ei,
                                 double* __restrict__ edge_part) {
    __shared__ double smem1[8];
    __shared__ double smem2[8];

    float s1 = 0.f, s2 = 0.f;
    const int gid = blockIdx.x * blockDim.x + threadIdx.x;
    const int stride = gridDim.x * blockDim.x;
    const int ngroups = N_EDGES / 8;     // 2M groups of 8 edges
    const vint4* eia = (const vint4*)ei;
    const vint4* eib = (const vint4*)(ei + N_EDGES);

    int g = gid;
    if (g < ngroups) {
        vint4 a0 = __builtin_nontemporal_load(eia + 2 * g);
        vint4 a1 = __builtin_nontemporal_load(eia + 2 * g + 1);
        vint4 b0 = __builtin_nontemporal_load(eib + 2 * g);
        vint4 b1 = __builtin_nontemporal_load(eib + 2 * g + 1);
        while (true) {
            // 16 gathers issued back-to-back
            unsigned pa0 = packed[a0.x], pa1 = packed[a0.y];
            unsigned pa2 = packed[a0.z], pa3 = packed[a0.w];
            unsigned pa4 = packed[a1.x], pa5 = packed[a1.y];
            unsigned pa6 = packed[a1.z], pa7 = packed[a1.w];
            unsigned pb0 = packed[b0.x], pb1 = packed[b0.y];
            unsigned pb2 = packed[b0.z], pb3 = packed[b0.w];
            unsigned pb4 = packed[b1.x], pb5 = packed[b1.y];
            unsigned pb6 = packed[b1.z], pb7 = packed[b1.w];

            // prefetch next iteration's indices
            const int gn = g + stride;
            const bool more = gn < ngroups;
            vint4 a0n = {0,0,0,0}, a1n = {0,0,0,0};
            vint4 b0n = {0,0,0,0}, b1n = {0,0,0,0};
            if (more) {
                a0n = __builtin_nontemporal_load(eia + 2 * gn);
                a1n = __builtin_nontemporal_load(eia + 2 * gn + 1);
                b0n = __builtin_nontemporal_load(eib + 2 * gn);
                b1n = __builtin_nontemporal_load(eib + 2 * gn + 1);
            }

            EDGE_ACC(pa0, pb0); EDGE_ACC(pa1, pb1);
            EDGE_ACC(pa2, pb2); EDGE_ACC(pa3, pb3);
            EDGE_ACC(pa4, pb4); EDGE_ACC(pa5, pb5);
            EDGE_ACC(pa6, pb6); EDGE_ACC(pa7, pb7);

            if (!more) break;
            g = gn; a0 = a0n; a1 = a1n; b0 = b0n; b1 = b1n;
        }
    }
    edge_flush(s1, s2, edge_part, smem1, smem2);
}

// Fallback (ws too small for packed table): float2 gathers from pred.
__global__ void edge_pass_f32(const float2* __restrict__ pred,
                              const int* __restrict__ ei,
                              double* __restrict__ edge_part) {
    __shared__ double smem1[8];
    __shared__ double smem2[8];

    float s1 = 0.f, s2 = 0.f;
    const int idx = blockIdx.x * blockDim.x + threadIdx.x;
    const int stride = gridDim.x * blockDim.x;
    for (int e = idx; e < N_EDGES; e += stride) {
        int i = ei[e];
        int j = ei[N_EDGES + e];
        float2 pi = pred[i];
        float2 pj = pred[j];
        float dx = pi.x - pj.x, dy = pi.y - pj.y;
        float l2 = dx * dx + dy * dy;
        s2 += l2;
        s1 += sqrtf(l2);
    }
    edge_flush(s1, s2, edge_part, smem1, smem2);
}

// ---------------------------------------------------------------- finalize
__device__ __forceinline__ double block_reduce_256(double v, double* sm) {
    #pragma unroll
    for (int off = 32; off > 0; off >>= 1) v += __shfl_down(v, off);
    const int lane = threadIdx.x & 63;
    const int wid  = threadIdx.x >> 6;
    __syncthreads();
    if (lane == 0) sm[wid] = v;
    __syncthreads();
    return sm[0] + sm[1] + sm[2] + sm[3];
}

__global__ void finalize(const double* __restrict__ edge_part,
                         const double* __restrict__ recon_part,
                         const double* __restrict__ kl_part,
                         const float*  __restrict__ gsum_part,
                         const int*    __restrict__ epoch_p,
                         float* __restrict__ out) {
    __shared__ double sx_s[256], sy_s[256], sc_s[256];
    __shared__ double sm[8];

    const int t = threadIdx.x;

    double reconv = 0.0;
    for (int b = t; b < NODE_BLOCKS; b += 256) reconv += recon_part[b];
    double s1 = 0.0, s2 = 0.0;
    for (int b = t; b < EDGE_BLOCKS; b += 256) {
        s1 += edge_part[2 * b];
        s2 += edge_part[2 * b + 1];
    }

    {
        const int g = t & 63, q = t >> 6;
        double gx = 0.0, gy = 0.0, gc = 0.0;
        for (int b = q; b < NODE_BLOCKS; b += 4) {
            const float* slot = gsum_part + (size_t)b * 192;
            gx += slot[g]; gy += slot[64 + g]; gc += slot[128 + g];
        }
        sx_s[t] = gx; sy_s[t] = gy; sc_s[t] = gc;
    }
    __syncthreads();

    double drift = 0.0;
    if (t < 64) {
        double X = sx_s[t] + sx_s[t + 64] + sx_s[t + 128] + sx_s[t + 192];
        double Y = sy_s[t] + sy_s[t + 64] + sy_s[t + 128] + sy_s[t + 192];
        double C = sc_s[t] + sc_s[t + 64] + sc_s[t + 128] + sc_s[t + 192];
        double mx = X / C, my = Y / C;
        drift = mx * mx + my * my;
    }
    #pragma unroll
    for (int off = 32; off > 0; off >>= 1) drift += __shfl_down(drift, off);

    reconv = block_reduce_256(reconv, sm);
    s1     = block_reduce_256(s1, sm);
    s2     = block_reduce_256(s2, sm);

    if (t == 0) {
        double recon = reconv / (2.0 * (double)N_NODES);
        double lap   = s2 / (double)N_EDGES;
        double arap  = (s2 - s1 * s1 / (double)N_EDGES) / ((double)N_EDGES - 1.0);
        double drft  = drift / (double)NUM_GRAPHS;
        double kl    = -0.5 * kl_part[0] / (double)NUM_GRAPHS;
        int epoch = *epoch_p;
        double beta = (epoch < 10) ? ((double)epoch / 10.0) : 1.0;
        out[0] = (float)(recon + 0.1 * lap + 0.01 * drft + 0.1 * arap + beta * kl);
    }
}

extern "C" void kernel_launch(void* const* d_in, const int* in_sizes, int n_in,
                              void* d_out, int out_size, void* d_ws, size_t ws_size,
                              hipStream_t stream) {
    const float2* pred   = (const float2*)d_in[0];
    const float2* targ   = (const float2*)d_in[1];
    const int*    ei     = (const int*)d_in[2];
    const int*    batch  = (const int*)d_in[3];
    const float*  mu     = (const float*)d_in[4];
    const float*  logvar = (const float*)d_in[5];
    const int*    epoch  = (const int*)d_in[6];
    float* out = (float*)d_out;

    char* ws = (char*)d_ws;
    double* edge_part  = (double*)(ws + EDGE_PART_OFF);
    double* recon_part = (double*)(ws + RECON_PART_OFF);
    double* kl_part    = (double*)(ws + KL_PART_OFF);
    float*  gsum_part  = (float*)(ws + GSUM_PART_OFF);

    const bool use_packed = ws_size >= WS_NEEDED;
    uint2* packed2 = use_packed ? (uint2*)(ws + PACKED_OFF) : (uint2*)nullptr;

    node_kl_pass<<<NODE_BLOCKS, 256, 0, stream>>>(
        (const float4*)pred, (const float4*)targ, (const int2*)batch,
        mu, logvar, recon_part, kl_part, gsum_part, packed2);
    if (use_packed)
        edge_pass_packed<<<EDGE_BLOCKS, 256, 0, stream>>>(
            (const unsigned*)(ws + PACKED_OFF), ei, edge_part);
    else
        edge_pass_f32<<<EDGE_BLOCKS, 256, 0, stream>>>(pred, ei, edge_part);
    finalize<<<1, 256, 0, stream>>>(edge_part, recon_part, kl_part, gsum_part,
                                    epoch, out);
}